// Round 17
// baseline (220.526 us; speedup 1.0000x reference)
//
#include <hip/hip_runtime.h>
#include <hip/hip_bf16.h>

#define Bdim 32
#define Ndim 4096
#define Cdim 768
#define Kdim 64

typedef float f32x4 __attribute__((ext_vector_type(4)));
typedef short s16x8 __attribute__((ext_vector_type(8)));
typedef __bf16 bf16x8 __attribute__((ext_vector_type(8)));

__device__ __forceinline__ short f2bf(float f) {
  return __builtin_bit_cast(short, (__bf16)f);   // hw RNE cvt
}
__device__ __forceinline__ float bf2f(short s) {
  return (float)__builtin_bit_cast(__bf16, s);
}
__device__ __forceinline__ f32x4 MFMA(s16x8 a, s16x8 b, f32x4 c) {
  return __builtin_amdgcn_mfma_f32_16x16x32_bf16(
      __builtin_bit_cast(bf16x8, a), __builtin_bit_cast(bf16x8, b), c, 0, 0, 0);
}

// ---------------- k0: W fp32 -> bf16, fragment-order layout ----------------
__global__ void k0_wcvt(const float* __restrict__ W, short* __restrict__ Wr) {
  int idx = blockIdx.x * 256 + threadIdx.x;  // chunk of 8 elems; K*C/8 = 6144
  if (idx >= Kdim * Cdim / 8) return;
  int k = idx / (Cdim / 8), c8 = idx % (Cdim / 8);
  int cs = c8 >> 2, g = c8 & 3;
  int t = k >> 4, i = k & 15;
  const float* src = W + (size_t)k * Cdim + c8 * 8;
  s16x8 v;
#pragma unroll
  for (int e = 0; e < 8; ++e) v[e] = f2bf(src[e]);
  *(s16x8*)(Wr + ((((size_t)cs * 4 + t) * 4 + g) * 16 + i) * 8) = v;
}

// ---------------- k1: P = bf16(exp(x @ W^T)) (exotic layout) + tile sums ----------
// (R12-proven form: 24 loads in flight per group, exp folded into epilogue.)
__global__ __launch_bounds__(256) void k1_logits(
    const float* __restrict__ x, const short* __restrict__ Wr,
    short* __restrict__ P, float* __restrict__ ps) {
  const int blk = blockIdx.x;
  const int b = blk >> 6;          // 64 ntiles per batch
  const int ntile = blk & 63;      // 64 rows per tile
  const int tid = threadIdx.x;
  const int w = tid >> 6;
  const int l = tid & 63;
  const int g = l >> 4, i = l & 15;

  const float* xrow = x + (size_t)(b * Ndim + ntile * 64 + w * 16 + i) * Cdim;
  f32x4 acc[4] = {};

  for (int grp = 0; grp < 6; ++grp) {   // 6 groups x (4 cs-steps of K=32)
    const int cbase = grp * 128 + g * 8;
    f32x4 xv[8];
    s16x8 wv[4][4];
#pragma unroll
    for (int s = 0; s < 4; ++s) {
      const f32x4* ap = (const f32x4*)(xrow + cbase + s * 32);
      xv[2 * s] = ap[0];
      xv[2 * s + 1] = ap[1];
    }
#pragma unroll
    for (int s = 0; s < 4; ++s) {
#pragma unroll
      for (int t = 0; t < 4; ++t) {
        wv[s][t] = *(const s16x8*)(
            Wr + ((((size_t)(grp * 4 + s) * 4 + t) * 4 + g) * 16 + i) * 8);
      }
    }
#pragma unroll
    for (int s = 0; s < 4; ++s) {
      s16x8 af;
#pragma unroll
      for (int e = 0; e < 4; ++e) af[e] = f2bf(xv[2 * s][e]);
#pragma unroll
      for (int e = 0; e < 4; ++e) af[4 + e] = f2bf(xv[2 * s + 1][e]);
#pragma unroll
      for (int t = 0; t < 4; ++t) acc[t] = MFMA(af, wv[s][t], acc[t]);
    }
  }

  // epilogue: P = bf16(exp(logit)), store + per-tile sum (no max needed)
  short* Pb = P + (size_t)b * (Ndim * Kdim);
  float sv[4];
#pragma unroll
  for (int t = 0; t < 4; ++t) {
    sv[t] = 0.f;
#pragma unroll
    for (int r = 0; r < 4; ++r) {
      int n = ntile * 64 + w * 16 + g * 4 + r;  // D row = 4*(l>>4)+reg
      int k = t * 16 + i;                       // D col = l&15
      short hv = f2bf(__expf(acc[t][r]));
      Pb[(n >> 3) * 512 + k * 8 + (n & 7)] = hv;
      sv[t] += bf2f(hv);                        // sum the ROUNDED values
    }
    sv[t] += __shfl_xor(sv[t], 16);
    sv[t] += __shfl_xor(sv[t], 32);
  }
  __shared__ float rs[4][4][16];  // [w][t][i]
  if (g == 0) {
#pragma unroll
    for (int t = 0; t < 4; ++t) rs[w][t][i] = sv[t];
  }
  __syncthreads();
  if (w == 0 && g == 0) {
#pragma unroll
    for (int t = 0; t < 4; ++t) {
      float S = rs[0][t][i] + rs[1][t][i] + rs[2][t][i] + rs[3][t][i];
      ps[((size_t)b * 64 + ntile) * 64 + t * 16 + i] = S;
    }
  }
}

// ---------------- k2b: sum 64 tile-sums -> 1/denom (coalesced, R14-proven) --------
__global__ __launch_bounds__(256) void k2b_combine(
    const float* __restrict__ ps, float* __restrict__ invd) {
  const int b = blockIdx.x;
  const int t = threadIdx.x;
  const int k = t & 63, nt4 = t >> 6;
  float S = 0.f;
#pragma unroll
  for (int j = 0; j < 16; ++j)
    S += ps[((size_t)b * 64 + nt4 * 16 + j) * 64 + k];
  __shared__ float ss[4][64];
  ss[nt4][k] = S;
  __syncthreads();
  if (nt4 == 0) {
    float St = ss[0][k] + ss[1][k] + ss[2][k] + ss[3][k];
    invd[b * 64 + k] = 1.f / St;
  }
}

// ---------------- k3-v2: big-tile thin GEMM: part_q[b, 64k, 256c-slab] ------------
// Per block: 64k x 256c over 512 n. K-step = 64n staged fp32->bf16 into 32KB
// LDS (double-buffered, 64KB). 16 f32x4/thread of next-step x stay in flight
// through COMPUTE (64KB/block in flight -> Little's-law deep). 32 MFMA/thread
// per step. One soft barrier per step.
#define NQ2 8            // n-splits (512 n each)
#define CSLAB 256        // c-cols per block
#define KST 64           // n per K-step
#define STEPS 8          // 512 / 64
#define BUFSH (CSLAB * KST)      // shorts per LDS buffer (32KB)
__device__ __forceinline__ int swz(int c) {
  return ((((c >> 3) ^ c) & 7) << 4);  // byte-XOR, 16B granular
}
__global__ __launch_bounds__(256) void k3_tokens(
    const float* __restrict__ x, const short* __restrict__ P,
    float* __restrict__ part) {
  __shared__ short xs[2 * BUFSH];  // 64KB: 2 x [c:256][n:64] rows of 128B
  char* xsb = (char*)xs;
  const int blk = blockIdx.x;
  const int cb = blk % 3;
  const int q = (blk / 3) & 7;
  const int b = blk / 24;
  const int tid = threadIdx.x;
  const int w = tid >> 6, l = tid & 63, g = l >> 4, i = l & 15;

  const float* xb = x + (size_t)b * Ndim * Cdim + cb * CSLAB;
  const short* Pb = P + (size_t)b * (Ndim * Kdim);
  const int n0 = q * 512;

  f32x4 acc[4][4] = {};  // [kt][ct]
  f32x4 sr[4][4];        // staging: 4 units x {row n2: 2 vec, row n2+1: 2 vec}

#define LOADS(s)                                                              \
  do {                                                                        \
    _Pragma("unroll") for (int uu = 0; uu < 4; ++uu) {                        \
      int u_ = tid + uu * 256;                                                \
      int n2_ = (u_ >> 5) * 2, cu_ = u_ & 31;                                 \
      const f32x4* p0_ =                                                      \
          (const f32x4*)(xb + (size_t)(n0 + (s) * KST + n2_) * Cdim + cu_ * 8);\
      const f32x4* p1_ =                                                      \
          (const f32x4*)(xb + (size_t)(n0 + (s) * KST + n2_ + 1) * Cdim + cu_ * 8);\
      sr[uu][0] = p0_[0];                                                     \
      sr[uu][1] = p0_[1];                                                     \
      sr[uu][2] = p1_[0];                                                     \
      sr[uu][3] = p1_[1];                                                     \
    }                                                                         \
  } while (0)

#define WRITE(base)                                                           \
  do {                                                                        \
    _Pragma("unroll") for (int uu = 0; uu < 4; ++uu) {                        \
      int u_ = tid + uu * 256;                                                \
      int n2_ = (u_ >> 5) * 2, cu_ = u_ & 31;                                 \
      _Pragma("unroll") for (int e = 0; e < 8; ++e) {                         \
        int c_ = cu_ * 8 + e;                                                 \
        float v0_ = (e < 4) ? sr[uu][0][e] : sr[uu][1][e - 4];                \
        float v1_ = (e < 4) ? sr[uu][2][e] : sr[uu][3][e - 4];                \
        unsigned pk_ = (unsigned)(unsigned short)f2bf(v0_) |                  \
                       ((unsigned)(unsigned short)f2bf(v1_) << 16);           \
        *(unsigned*)(xsb + (base) + c_ * 128 + ((2 * n2_) ^ swz(c_))) = pk_;  \
      }                                                                       \
    }                                                                         \
  } while (0)

#define COMPUTE(base, s)                                                      \
  do {                                                                        \
    s16x8 A_[4][2];                                                           \
    _Pragma("unroll") for (int kt = 0; kt < 4; ++kt)                          \
    _Pragma("unroll") for (int ns = 0; ns < 2; ++ns)                          \
        A_[kt][ns] = *(const s16x8*)(                                         \
            Pb + ((size_t)(n0 / 8 + (s) * 8 + ns * 4 + g)) * 512 +            \
            (kt * 16 + i) * 8);                                               \
    _Pragma("unroll") for (int ct = 0; ct < 4; ++ct) {                        \
      const int c_ = w * 64 + ct * 16 + i;                                    \
      _Pragma("unroll") for (int ns = 0; ns < 2; ++ns) {                      \
        const int noff_ = ns * 32 + g * 8;                                    \
        s16x8 B_ = *(const s16x8*)(xsb + (base) + c_ * 128 +                  \
                                   ((2 * noff_) ^ swz(c_)));                  \
        _Pragma("unroll") for (int kt = 0; kt < 4; ++kt)                      \
            acc[kt][ct] = MFMA(A_[kt][ns], B_, acc[kt][ct]);                  \
      }                                                                       \
    }                                                                         \
  } while (0)

#define SOFT_BARRIER()                                                        \
  do {                                                                        \
    asm volatile("s_waitcnt lgkmcnt(0)" ::: "memory");                        \
    __builtin_amdgcn_s_barrier();                                             \
    __builtin_amdgcn_sched_barrier(0);                                        \
  } while (0)

  // prologue: stage step 0
  LOADS(0);
  WRITE(0);
  SOFT_BARRIER();
#pragma unroll 2
  for (int s = 0; s < STEPS; ++s) {
    const int cur = (s & 1) * (BUFSH * 2);        // byte offset of current buf
    const int nxt = ((s + 1) & 1) * (BUFSH * 2);
    if (s + 1 < STEPS) LOADS(s + 1);              // 64KB/block stays in flight
    COMPUTE(cur, s);
    if (s + 1 < STEPS) WRITE(nxt);                // vmcnt hidden under COMPUTE
    SOFT_BARRIER();
  }

  float* pb = part + ((size_t)q * Bdim + b) * (Kdim * Cdim);
#pragma unroll
  for (int kt = 0; kt < 4; ++kt) {
#pragma unroll
    for (int r = 0; r < 4; ++r) {
      const int k = kt * 16 + g * 4 + r;
#pragma unroll
      for (int ct = 0; ct < 4; ++ct) {
        const int c = cb * CSLAB + w * 64 + ct * 16 + i;
        pb[(size_t)k * Cdim + c] = acc[kt][ct][r];
      }
    }
  }
#undef LOADS
#undef WRITE
#undef COMPUTE
#undef SOFT_BARRIER
}

// ---------------- k4: out = invd * sum_q part[q] (8 slices) ----------------
#define QSTRIDE (Bdim * Kdim * Cdim / 4)  // f32x4 units per q-slice = 393216
__global__ __launch_bounds__(256) void k4_reduce(
    const float* __restrict__ part, const float* __restrict__ invd,
    float* __restrict__ out) {
  const int idx = blockIdx.x * 256 + threadIdx.x;
  const f32x4* p = (const f32x4*)part;
  f32x4 s = p[idx] + p[idx + QSTRIDE];
#pragma unroll
  for (int j = 2; j < NQ2; ++j) s += p[idx + (size_t)j * QSTRIDE];
  const float sc = invd[(idx * 4) / Cdim];  // (b*64+k)
  ((f32x4*)out)[idx] = s * sc;
}

extern "C" void kernel_launch(void* const* d_in, const int* in_sizes, int n_in,
                              void* d_out, int out_size, void* d_ws, size_t ws_size,
                              hipStream_t stream) {
  const float* x = (const float*)d_in[0];
  const float* W = (const float*)d_in[1];
  float* out = (float*)d_out;
  char* ws = (char*)d_ws;

  short* Wb = (short*)ws;                                   // 96 KB (pad 128K)
  short* P = (short*)(ws + (1 << 17));                      // 16 MB bf16 exp-logits
  char* after = ws + (1 << 17) + (size_t)Bdim * Ndim * Kdim * 2;
  float* psum = (float*)after;                              // [32][64][64] tile sums
  float* iv = psum + Bdim * 64 * 64;                        // 2048 inv-denom
  float* part = iv + Bdim * Kdim;                           // [8][32][64][768] fp32, 50MB

  hipLaunchKernelGGL(k0_wcvt, dim3(24), dim3(256), 0, stream, W, Wb);
  hipLaunchKernelGGL(k1_logits, dim3(Bdim * 64), dim3(256), 0, stream, x, Wb, P, psum);
  hipLaunchKernelGGL(k2b_combine, dim3(Bdim), dim3(256), 0, stream, psum, iv);
  hipLaunchKernelGGL(k3_tokens, dim3(Bdim * 3 * NQ2), dim3(256), 0, stream, x, P, part);
  hipLaunchKernelGGL(k4_reduce, dim3(Bdim * Kdim * Cdim / 4 / 256), dim3(256), 0, stream,
                     part, iv, out);
}

// Round 18
// 205.910 us; speedup vs baseline: 1.0710x; 1.0710x over previous
//
#include <hip/hip_runtime.h>
#include <hip/hip_bf16.h>

#define Bdim 32
#define Ndim 4096
#define Cdim 768
#define Kdim 64

typedef float f32x4 __attribute__((ext_vector_type(4)));
typedef short s16x8 __attribute__((ext_vector_type(8)));
typedef __bf16 bf16x8 __attribute__((ext_vector_type(8)));

__device__ __forceinline__ short f2bf(float f) {
  return __builtin_bit_cast(short, (__bf16)f);   // hw RNE cvt
}
__device__ __forceinline__ float bf2f(short s) {
  return (float)__builtin_bit_cast(__bf16, s);
}
__device__ __forceinline__ f32x4 MFMA(s16x8 a, s16x8 b, f32x4 c) {
  return __builtin_amdgcn_mfma_f32_16x16x32_bf16(
      __builtin_bit_cast(bf16x8, a), __builtin_bit_cast(bf16x8, b), c, 0, 0, 0);
}

// ---------------- k0: W fp32 -> bf16, fragment-order layout ----------------
__global__ void k0_wcvt(const float* __restrict__ W, short* __restrict__ Wr) {
  int idx = blockIdx.x * 256 + threadIdx.x;  // chunk of 8 elems; K*C/8 = 6144
  if (idx >= Kdim * Cdim / 8) return;
  int k = idx / (Cdim / 8), c8 = idx % (Cdim / 8);
  int cs = c8 >> 2, g = c8 & 3;
  int t = k >> 4, i = k & 15;
  const float* src = W + (size_t)k * Cdim + c8 * 8;
  s16x8 v;
#pragma unroll
  for (int e = 0; e < 8; ++e) v[e] = f2bf(src[e]);
  *(s16x8*)(Wr + ((((size_t)cs * 4 + t) * 4 + g) * 16 + i) * 8) = v;
}

// ---------------- k1: P = bf16(exp(x @ W^T)) (exotic layout) + tile sums ----------
// (R12-proven form: 24 loads in flight per group, exp folded into epilogue.)
__global__ __launch_bounds__(256) void k1_logits(
    const float* __restrict__ x, const short* __restrict__ Wr,
    short* __restrict__ P, float* __restrict__ ps) {
  const int blk = blockIdx.x;
  const int b = blk >> 6;          // 64 ntiles per batch
  const int ntile = blk & 63;      // 64 rows per tile
  const int tid = threadIdx.x;
  const int w = tid >> 6;
  const int l = tid & 63;
  const int g = l >> 4, i = l & 15;

  const float* xrow = x + (size_t)(b * Ndim + ntile * 64 + w * 16 + i) * Cdim;
  f32x4 acc[4] = {};

  for (int grp = 0; grp < 6; ++grp) {   // 6 groups x (4 cs-steps of K=32)
    const int cbase = grp * 128 + g * 8;
    f32x4 xv[8];
    s16x8 wv[4][4];
#pragma unroll
    for (int s = 0; s < 4; ++s) {
      const f32x4* ap = (const f32x4*)(xrow + cbase + s * 32);
      xv[2 * s] = ap[0];
      xv[2 * s + 1] = ap[1];
    }
#pragma unroll
    for (int s = 0; s < 4; ++s) {
#pragma unroll
      for (int t = 0; t < 4; ++t) {
        wv[s][t] = *(const s16x8*)(
            Wr + ((((size_t)(grp * 4 + s) * 4 + t) * 4 + g) * 16 + i) * 8);
      }
    }
#pragma unroll
    for (int s = 0; s < 4; ++s) {
      s16x8 af;
#pragma unroll
      for (int e = 0; e < 4; ++e) af[e] = f2bf(xv[2 * s][e]);
#pragma unroll
      for (int e = 0; e < 4; ++e) af[4 + e] = f2bf(xv[2 * s + 1][e]);
#pragma unroll
      for (int t = 0; t < 4; ++t) acc[t] = MFMA(af, wv[s][t], acc[t]);
    }
  }

  // epilogue: P = bf16(exp(logit)), store + per-tile sum (no max needed)
  short* Pb = P + (size_t)b * (Ndim * Kdim);
  float sv[4];
#pragma unroll
  for (int t = 0; t < 4; ++t) {
    sv[t] = 0.f;
#pragma unroll
    for (int r = 0; r < 4; ++r) {
      int n = ntile * 64 + w * 16 + g * 4 + r;  // D row = 4*(l>>4)+reg
      int k = t * 16 + i;                       // D col = l&15
      short hv = f2bf(__expf(acc[t][r]));
      Pb[(n >> 3) * 512 + k * 8 + (n & 7)] = hv;
      sv[t] += bf2f(hv);                        // sum the ROUNDED values
    }
    sv[t] += __shfl_xor(sv[t], 16);
    sv[t] += __shfl_xor(sv[t], 32);
  }
  __shared__ float rs[4][4][16];  // [w][t][i]
  if (g == 0) {
#pragma unroll
    for (int t = 0; t < 4; ++t) rs[w][t][i] = sv[t];
  }
  __syncthreads();
  if (w == 0 && g == 0) {
#pragma unroll
    for (int t = 0; t < 4; ++t) {
      float S = rs[0][t][i] + rs[1][t][i] + rs[2][t][i] + rs[3][t][i];
      ps[((size_t)b * 64 + ntile) * 64 + t * 16 + i] = S;
    }
  }
}

// ---------------- k2b: sum 64 tile-sums -> 1/denom (coalesced, R14-proven) --------
__global__ __launch_bounds__(256) void k2b_combine(
    const float* __restrict__ ps, float* __restrict__ invd) {
  const int b = blockIdx.x;
  const int t = threadIdx.x;
  const int k = t & 63, nt4 = t >> 6;
  float S = 0.f;
#pragma unroll
  for (int j = 0; j < 16; ++j)
    S += ps[((size_t)b * 64 + nt4 * 16 + j) * 64 + k];
  __shared__ float ss[4][64];
  ss[nt4][k] = S;
  __syncthreads();
  if (nt4 == 0) {
    float St = ss[0][k] + ss[1][k] + ss[2][k] + ss[3][k];
    invd[b * 64 + k] = 1.f / St;
  }
}

// ---------------- k3: out[b,k,c] += invd[k] * sum_{n in q} P[n,k]*x[b,n,c] ---------
// R14-proven core (dbuf LDS, one soft barrier per chunk, q fastest-varying).
// NEW: epilogue scales by invd and unsafeAtomicAdds straight into out (out is
// zeroed by hipMemsetAsync before this kernel) -> k4 and the 56MB part
// round-trip are gone. sum_q(inv*part_q) == inv*sum_q(part_q) exactly.
#define CT 48    // c-columns per block
#define NCH 128  // n rows staged per chunk
#define NQ 4     // n-splits
#define BUFO (CT * 128)  // shorts per LDS buffer
__device__ __forceinline__ int swz(int c) {
  return ((((c >> 3) ^ c) & 7) << 4);  // byte-XOR within a 256B row
}
__global__ __launch_bounds__(256) void k3_tokens(
    const float* __restrict__ x, const short* __restrict__ P,
    const float* __restrict__ invd, float* __restrict__ out) {
  __shared__ short xs[2 * BUFO];  // 2 x (CT rows x 256 bytes)
  char* xsb = (char*)xs;
  const int blk = blockIdx.x;
  const int q = blk & 3;
  const int ct = (blk >> 2) & 15;
  const int b = blk >> 6;
  const int tid = threadIdx.x;
  const int w = tid >> 6, l = tid & 63, g = l >> 4, i = l & 15;

  const float* xb = x + (size_t)b * Ndim * Cdim;
  const short* Pb = P + (size_t)b * (Ndim * Kdim);

  // preload invd for this lane's 4 output rows (L2-hot, 4 scalar loads)
  float iv4[4];
#pragma unroll
  for (int r = 0; r < 4; ++r) iv4[r] = invd[b * 64 + w * 16 + g * 4 + r];

  f32x4 acc[3] = {};

#define LOADX(ch, buf)                                                        \
  do {                                                                        \
    const int n0_ = (ch) * NCH;                                               \
    _Pragma("unroll") for (int uu = 0; uu < 3; ++uu) {                        \
      int u_ = tid + uu * 256;                                                \
      int n_ = u_ / 6, c8_ = u_ % 6;                                          \
      const f32x4* src_ =                                                     \
          (const f32x4*)(xb + (size_t)(n0_ + n_) * Cdim + ct * CT + c8_ * 8); \
      buf[uu][0] = src_[0];                                                   \
      buf[uu][1] = src_[1];                                                   \
    }                                                                         \
  } while (0)

#define LOADL(ch, lvb)                                                        \
  do {                                                                        \
    const int nb8_ = (ch) * 16;                                               \
    _Pragma("unroll") for (int ns = 0; ns < 4; ++ns) {                        \
      lvb[ns] = *(const s16x8*)(Pb + (size_t)(nb8_ + ns * 4 + g) * 512 +      \
                                (w * 16 + i) * 8);                            \
    }                                                                         \
  } while (0)

#define STORELDS(base, buf)                                                   \
  do {                                                                        \
    _Pragma("unroll") for (int uu = 0; uu < 3; ++uu) {                        \
      int u_ = tid + uu * 256;                                                \
      int n_ = u_ / 6, c8_ = u_ % 6;                                          \
      _Pragma("unroll") for (int e = 0; e < 8; ++e) {                         \
        int c_ = c8_ * 8 + e;                                                 \
        float fv_ = (e < 4) ? buf[uu][0][e] : buf[uu][1][e - 4];              \
        *(short*)(xsb + (base) + c_ * 256 + ((2 * n_) ^ swz(c_))) = f2bf(fv_);\
      }                                                                       \
    }                                                                         \
  } while (0)

#define COMPUTE(base, lvb)                                                    \
  do {                                                                        \
    _Pragma("unroll") for (int ns = 0; ns < 4; ++ns) {                        \
      _Pragma("unroll") for (int cs = 0; cs < 3; ++cs) {                      \
        const int c_ = cs * 16 + i;                                           \
        s16x8 bfr_ = *(const s16x8*)(xsb + (base) + c_ * 256 +                \
                                     ((ns * 64 + g * 16) ^ swz(c_)));         \
        acc[cs] = MFMA(lvb[ns], bfr_, acc[cs]);                               \
      }                                                                       \
    }                                                                         \
  } while (0)

#define SOFT_BARRIER()                                                        \
  do {                                                                        \
    asm volatile("s_waitcnt lgkmcnt(0)" ::: "memory");                        \
    __builtin_amdgcn_s_barrier();                                             \
    __builtin_amdgcn_sched_barrier(0);                                        \
  } while (0)

  f32x4 stA[3][2], stB[3][2];
  s16x8 lvA[4], lvB[4];

  const int ch0 = q * 8;  // 8 chunks of 128 n per block
  LOADX(ch0, stA);
  LOADL(ch0, lvA);
  LOADX(ch0 + 1, stB);
  LOADL(ch0 + 1, lvB);
  STORELDS(0, stA);
  SOFT_BARRIER();

  for (int c = 0; c < 8; c += 2) {
    if (c + 2 < 8) LOADX(ch0 + c + 2, stA);
    STORELDS(BUFO * 2, stB);
    COMPUTE(0, lvA);
    if (c + 2 < 8) LOADL(ch0 + c + 2, lvA);
    SOFT_BARRIER();
    if (c + 3 < 8) LOADX(ch0 + c + 3, stB);
    if (c + 2 < 8) STORELDS(0, stA);
    COMPUTE(BUFO * 2, lvB);
    if (c + 3 < 8) LOADL(ch0 + c + 3, lvB);
    SOFT_BARRIER();
  }

  // epilogue: scaled atomic accumulate into out (zeroed via memset)
  float* ob = out + (size_t)b * (Kdim * Cdim);
#pragma unroll
  for (int r = 0; r < 4; ++r) {
    const int k = w * 16 + g * 4 + r;
#pragma unroll
    for (int cs = 0; cs < 3; ++cs) {
      unsafeAtomicAdd(&ob[(size_t)k * Cdim + ct * CT + cs * 16 + i],
                      acc[cs][r] * iv4[r]);
    }
  }
#undef LOADX
#undef LOADL
#undef STORELDS
#undef COMPUTE
#undef SOFT_BARRIER
}

extern "C" void kernel_launch(void* const* d_in, const int* in_sizes, int n_in,
                              void* d_out, int out_size, void* d_ws, size_t ws_size,
                              hipStream_t stream) {
  const float* x = (const float*)d_in[0];
  const float* W = (const float*)d_in[1];
  float* out = (float*)d_out;
  char* ws = (char*)d_ws;

  short* Wb = (short*)ws;                                   // 96 KB (pad 128K)
  short* P = (short*)(ws + (1 << 17));                      // 16 MB bf16 exp-logits
  char* after = ws + (1 << 17) + (size_t)Bdim * Ndim * Kdim * 2;
  float* psum = (float*)after;                              // [32][64][64] tile sums
  float* iv = psum + Bdim * 64 * 64;                        // 2048 inv-denom

  hipLaunchKernelGGL(k0_wcvt, dim3(24), dim3(256), 0, stream, W, Wb);
  hipLaunchKernelGGL(k1_logits, dim3(Bdim * 64), dim3(256), 0, stream, x, Wb, P, psum);
  hipLaunchKernelGGL(k2b_combine, dim3(Bdim), dim3(256), 0, stream, psum, iv);
  hipMemsetAsync(out, 0, (size_t)out_size * sizeof(float), stream);
  hipLaunchKernelGGL(k3_tokens, dim3(Bdim * 16 * NQ), dim3(256), 0, stream,
                     x, P, iv, out);
}

// Round 19
// 201.173 us; speedup vs baseline: 1.0962x; 1.0235x over previous
//
#include <hip/hip_runtime.h>
#include <hip/hip_bf16.h>

#define Bdim 32
#define Ndim 4096
#define Cdim 768
#define Kdim 64

typedef float f32x4 __attribute__((ext_vector_type(4)));
typedef short s16x8 __attribute__((ext_vector_type(8)));
typedef __bf16 bf16x8 __attribute__((ext_vector_type(8)));

__device__ __forceinline__ short f2bf(float f) {
  return __builtin_bit_cast(short, (__bf16)f);   // hw RNE cvt
}
__device__ __forceinline__ float bf2f(short s) {
  return (float)__builtin_bit_cast(__bf16, s);
}
__device__ __forceinline__ f32x4 MFMA(s16x8 a, s16x8 b, f32x4 c) {
  return __builtin_amdgcn_mfma_f32_16x16x32_bf16(
      __builtin_bit_cast(bf16x8, a), __builtin_bit_cast(bf16x8, b), c, 0, 0, 0);
}

// ---------------- k0_init: W cvt (fragment order) + zero out + zero sums ----------
// Folds the former hipMemsetAsync(out) and k2b's input init into one dispatch.
__global__ __launch_bounds__(256) void k0_init(
    const float* __restrict__ W, short* __restrict__ Wr,
    float* __restrict__ sum, float* __restrict__ out) {
  const int idx = blockIdx.x * 256 + threadIdx.x;  // 0..98303 (384 blocks)
  // zero out[]: 393216 f32x4 units, 4 per thread, coalesced
  f32x4 z = {0.f, 0.f, 0.f, 0.f};
  f32x4* o4 = (f32x4*)out;
#pragma unroll
  for (int j = 0; j < 4; ++j) o4[idx + j * 98304] = z;
  if (idx < Bdim * Kdim) sum[idx] = 0.f;
  if (idx < Kdim * Cdim / 8) {
    int k = idx / (Cdim / 8), c8 = idx % (Cdim / 8);
    int cs = c8 >> 2, g = c8 & 3;
    int t = k >> 4, i = k & 15;
    const float* src = W + (size_t)k * Cdim + c8 * 8;
    s16x8 v;
#pragma unroll
    for (int e = 0; e < 8; ++e) v[e] = f2bf(src[e]);
    *(s16x8*)(Wr + ((((size_t)cs * 4 + t) * 4 + g) * 16 + i) * 8) = v;
  }
}

// ---------------- k1: P = bf16(exp(x @ W^T)) (exotic layout) + atomic sums --------
// R12-proven core. Epilogue now unsafeAtomicAdds tile sums into sum[b*64+k]
// (replaces psum store + the whole k2b kernel).
__global__ __launch_bounds__(256) void k1_logits(
    const float* __restrict__ x, const short* __restrict__ Wr,
    short* __restrict__ P, float* __restrict__ sum) {
  const int blk = blockIdx.x;
  const int b = blk >> 6;          // 64 ntiles per batch
  const int ntile = blk & 63;      // 64 rows per tile
  const int tid = threadIdx.x;
  const int w = tid >> 6;
  const int l = tid & 63;
  const int g = l >> 4, i = l & 15;

  const float* xrow = x + (size_t)(b * Ndim + ntile * 64 + w * 16 + i) * Cdim;
  f32x4 acc[4] = {};

  for (int grp = 0; grp < 6; ++grp) {   // 6 groups x (4 cs-steps of K=32)
    const int cbase = grp * 128 + g * 8;
    f32x4 xv[8];
    s16x8 wv[4][4];
#pragma unroll
    for (int s = 0; s < 4; ++s) {
      const f32x4* ap = (const f32x4*)(xrow + cbase + s * 32);
      xv[2 * s] = ap[0];
      xv[2 * s + 1] = ap[1];
    }
#pragma unroll
    for (int s = 0; s < 4; ++s) {
#pragma unroll
      for (int t = 0; t < 4; ++t) {
        wv[s][t] = *(const s16x8*)(
            Wr + ((((size_t)(grp * 4 + s) * 4 + t) * 4 + g) * 16 + i) * 8);
      }
    }
#pragma unroll
    for (int s = 0; s < 4; ++s) {
      s16x8 af;
#pragma unroll
      for (int e = 0; e < 4; ++e) af[e] = f2bf(xv[2 * s][e]);
#pragma unroll
      for (int e = 0; e < 4; ++e) af[4 + e] = f2bf(xv[2 * s + 1][e]);
#pragma unroll
      for (int t = 0; t < 4; ++t) acc[t] = MFMA(af, wv[s][t], acc[t]);
    }
  }

  // epilogue: P = bf16(exp(logit)), store + per-tile sum -> atomic accumulate
  short* Pb = P + (size_t)b * (Ndim * Kdim);
  float sv[4];
#pragma unroll
  for (int t = 0; t < 4; ++t) {
    sv[t] = 0.f;
#pragma unroll
    for (int r = 0; r < 4; ++r) {
      int n = ntile * 64 + w * 16 + g * 4 + r;  // D row = 4*(l>>4)+reg
      int k = t * 16 + i;                       // D col = l&15
      short hv = f2bf(__expf(acc[t][r]));
      Pb[(n >> 3) * 512 + k * 8 + (n & 7)] = hv;
      sv[t] += bf2f(hv);                        // sum the ROUNDED values
    }
    sv[t] += __shfl_xor(sv[t], 16);
    sv[t] += __shfl_xor(sv[t], 32);
  }
  __shared__ float rs[4][4][16];  // [w][t][i]
  if (g == 0) {
#pragma unroll
    for (int t = 0; t < 4; ++t) rs[w][t][i] = sv[t];
  }
  __syncthreads();
  if (w == 0 && g == 0) {
#pragma unroll
    for (int t = 0; t < 4; ++t) {
      float S = rs[0][t][i] + rs[1][t][i] + rs[2][t][i] + rs[3][t][i];
      unsafeAtomicAdd(&sum[b * 64 + t * 16 + i], S);
    }
  }
}

// ---------------- k3: out[b,k,c] += (1/sum[k]) * sum_{n in q} P[n,k]*x[b,n,c] ------
// R18-proven core (dbuf LDS, one soft barrier/chunk, atomic out-epilogue).
// NEW: prologue computes 1/sum itself (k2b gone); kernel-boundary ordering
// guarantees sum[] is complete.
#define CT 48    // c-columns per block
#define NCH 128  // n rows staged per chunk
#define NQ 4     // n-splits
#define BUFO (CT * 128)  // shorts per LDS buffer
__device__ __forceinline__ int swz(int c) {
  return ((((c >> 3) ^ c) & 7) << 4);  // byte-XOR within a 256B row
}
__global__ __launch_bounds__(256) void k3_tokens(
    const float* __restrict__ x, const short* __restrict__ P,
    const float* __restrict__ sum, float* __restrict__ out) {
  __shared__ short xs[2 * BUFO];  // 2 x (CT rows x 256 bytes)
  char* xsb = (char*)xs;
  const int blk = blockIdx.x;
  const int q = blk & 3;
  const int ct = (blk >> 2) & 15;
  const int b = blk >> 6;
  const int tid = threadIdx.x;
  const int w = tid >> 6, l = tid & 63, g = l >> 4, i = l & 15;

  const float* xb = x + (size_t)b * Ndim * Cdim;
  const short* Pb = P + (size_t)b * (Ndim * Kdim);

  // inv-denoms for this lane's 4 output rows (L2-hot loads + IEEE div)
  float iv4[4];
#pragma unroll
  for (int r = 0; r < 4; ++r) iv4[r] = 1.f / sum[b * 64 + w * 16 + g * 4 + r];

  f32x4 acc[3] = {};

#define LOADX(ch, buf)                                                        \
  do {                                                                        \
    const int n0_ = (ch) * NCH;                                               \
    _Pragma("unroll") for (int uu = 0; uu < 3; ++uu) {                        \
      int u_ = tid + uu * 256;                                                \
      int n_ = u_ / 6, c8_ = u_ % 6;                                          \
      const f32x4* src_ =                                                     \
          (const f32x4*)(xb + (size_t)(n0_ + n_) * Cdim + ct * CT + c8_ * 8); \
      buf[uu][0] = src_[0];                                                   \
      buf[uu][1] = src_[1];                                                   \
    }                                                                         \
  } while (0)

#define LOADL(ch, lvb)                                                        \
  do {                                                                        \
    const int nb8_ = (ch) * 16;                                               \
    _Pragma("unroll") for (int ns = 0; ns < 4; ++ns) {                        \
      lvb[ns] = *(const s16x8*)(Pb + (size_t)(nb8_ + ns * 4 + g) * 512 +      \
                                (w * 16 + i) * 8);                            \
    }                                                                         \
  } while (0)

#define STORELDS(base, buf)                                                   \
  do {                                                                        \
    _Pragma("unroll") for (int uu = 0; uu < 3; ++uu) {                        \
      int u_ = tid + uu * 256;                                                \
      int n_ = u_ / 6, c8_ = u_ % 6;                                          \
      _Pragma("unroll") for (int e = 0; e < 8; ++e) {                         \
        int c_ = c8_ * 8 + e;                                                 \
        float fv_ = (e < 4) ? buf[uu][0][e] : buf[uu][1][e - 4];              \
        *(short*)(xsb + (base) + c_ * 256 + ((2 * n_) ^ swz(c_))) = f2bf(fv_);\
      }                                                                       \
    }                                                                         \
  } while (0)

#define COMPUTE(base, lvb)                                                    \
  do {                                                                        \
    _Pragma("unroll") for (int ns = 0; ns < 4; ++ns) {                        \
      _Pragma("unroll") for (int cs = 0; cs < 3; ++cs) {                      \
        const int c_ = cs * 16 + i;                                           \
        s16x8 bfr_ = *(const s16x8*)(xsb + (base) + c_ * 256 +                \
                                     ((ns * 64 + g * 16) ^ swz(c_)));         \
        acc[cs] = MFMA(lvb[ns], bfr_, acc[cs]);                               \
      }                                                                       \
    }                                                                         \
  } while (0)

#define SOFT_BARRIER()                                                        \
  do {                                                                        \
    asm volatile("s_waitcnt lgkmcnt(0)" ::: "memory");                        \
    __builtin_amdgcn_s_barrier();                                             \
    __builtin_amdgcn_sched_barrier(0);                                        \
  } while (0)

  f32x4 stA[3][2], stB[3][2];
  s16x8 lvA[4], lvB[4];

  const int ch0 = q * 8;  // 8 chunks of 128 n per block
  LOADX(ch0, stA);
  LOADL(ch0, lvA);
  LOADX(ch0 + 1, stB);
  LOADL(ch0 + 1, lvB);
  STORELDS(0, stA);
  SOFT_BARRIER();

  for (int c = 0; c < 8; c += 2) {
    if (c + 2 < 8) LOADX(ch0 + c + 2, stA);
    STORELDS(BUFO * 2, stB);
    COMPUTE(0, lvA);
    if (c + 2 < 8) LOADL(ch0 + c + 2, lvA);
    SOFT_BARRIER();
    if (c + 3 < 8) LOADX(ch0 + c + 3, stB);
    if (c + 2 < 8) STORELDS(0, stA);
    COMPUTE(BUFO * 2, lvB);
    if (c + 3 < 8) LOADL(ch0 + c + 3, lvB);
    SOFT_BARRIER();
  }

  // epilogue: scaled atomic accumulate into out (zeroed by k0_init)
  float* ob = out + (size_t)b * (Kdim * Cdim);
#pragma unroll
  for (int r = 0; r < 4; ++r) {
    const int k = w * 16 + g * 4 + r;
#pragma unroll
    for (int cs = 0; cs < 3; ++cs) {
      unsafeAtomicAdd(&ob[(size_t)k * Cdim + ct * CT + cs * 16 + i],
                      acc[cs][r] * iv4[r]);
    }
  }
#undef LOADX
#undef LOADL
#undef STORELDS
#undef COMPUTE
#undef SOFT_BARRIER
}

extern "C" void kernel_launch(void* const* d_in, const int* in_sizes, int n_in,
                              void* d_out, int out_size, void* d_ws, size_t ws_size,
                              hipStream_t stream) {
  const float* x = (const float*)d_in[0];
  const float* W = (const float*)d_in[1];
  float* out = (float*)d_out;
  char* ws = (char*)d_ws;

  short* Wb = (short*)ws;                                   // 96 KB (pad 128K)
  short* P = (short*)(ws + (1 << 17));                      // 16 MB bf16 exp-logits
  float* sum = (float*)(ws + (1 << 17) + (size_t)Bdim * Ndim * Kdim * 2);  // 2048

  hipLaunchKernelGGL(k0_init, dim3(384), dim3(256), 0, stream, W, Wb, sum, out);
  hipLaunchKernelGGL(k1_logits, dim3(Bdim * 64), dim3(256), 0, stream, x, Wb, P, sum);
  hipLaunchKernelGGL(k3_tokens, dim3(Bdim * 16 * NQ), dim3(256), 0, stream,
                     x, P, sum, out);
}